// Round 2
// baseline (450.392 us; speedup 1.0000x reference)
//
#include <hip/hip_runtime.h>
#include <hip/hip_bf16.h>

#define NB 8
#define NC 256
#define ND 32
#define NN 16384
#define EPSF 1e-6f

typedef __attribute__((ext_vector_type(8))) short short8;
typedef __attribute__((ext_vector_type(4))) float float4v;

__device__ __forceinline__ float softplusf(float v) {
    return fmaxf(v, 0.0f) + log1pf(__expf(-fabsf(v)));
}

__device__ __forceinline__ unsigned short f2bf(float f) {
    __hip_bfloat16 h = __float2bfloat16(f);   // RNE
    return *reinterpret_cast<unsigned short*>(&h);
}
__device__ __forceinline__ unsigned int pk2bf(float lo, float hi) {
    return (unsigned int)f2bf(lo) | ((unsigned int)f2bf(hi) << 16);
}

// ---------------------------------------------------------------------------
// Kernel A (MFMA): per (b, 256-n tile), 8 chunks of 32 n.
//   K = softplus(wk@x + bk)  [32 x 32chunk]  via mfma (A=wk regs, B=xsT LDS)
//   KX[e][m] += sum_n x[e][n] * K[m][n]      via mfma (A=x global L1-hot, B=Klt LDS)
//   Ksum[m] += sum_n K[m][n]                 (shfl + atomic)
// block 256 = 4 waves. Wave roles K-phase: (mt=w&1, ct=w>>1). KX: et=4w+i.
// ---------------------------------------------------------------------------
__global__ __launch_bounds__(256) void kA(
    const float* __restrict__ x, const float* __restrict__ wk,
    const float* __restrict__ bk, float* __restrict__ part,
    float* __restrict__ kxf, float* __restrict__ ksum, int use_part)
{
    __shared__ __align__(16) unsigned char smem[35840];
    unsigned short* xsT = (unsigned short*)smem;            // [32 n][264 c] bf16
    float*          KXs = (float*)smem;                     // [32 m][260 e] fp32 (aliases xsT)
    unsigned short* Klt = (unsigned short*)(smem + 33280);  // [32 m][40 n] bf16

    const int t  = threadIdx.x;
    const int b  = blockIdx.x >> 6;
    const int n0 = (blockIdx.x & 63) << 8;
    const float* xb = x + (size_t)b * NC * NN;

    const int w = t >> 6, l = t & 63, q = l >> 4, ln = l & 15;
    const int mt = w & 1, ct = w >> 1;

    // preload wk A-frags: row m = 16mt+ln, k = 32ks+8q+j  (wk is 32KB, L2-hot)
    short8 wkf[8];
    #pragma unroll
    for (int ks = 0; ks < 8; ++ks) {
        const float* wp = wk + (16 * mt + ln) * 256 + 32 * ks + 8 * q;
        float4 a = *(const float4*)wp;
        float4 c = *(const float4*)(wp + 4);
        short8 f;
        f[0] = (short)f2bf(a.x); f[1] = (short)f2bf(a.y);
        f[2] = (short)f2bf(a.z); f[3] = (short)f2bf(a.w);
        f[4] = (short)f2bf(c.x); f[5] = (short)f2bf(c.y);
        f[6] = (short)f2bf(c.z); f[7] = (short)f2bf(c.w);
        wkf[ks] = f;
    }
    float bkr[4];
    #pragma unroll
    for (int r = 0; r < 4; ++r) bkr[r] = bk[16 * mt + 4 * q + r];

    float ksumacc[4] = {0.f, 0.f, 0.f, 0.f};
    float4v kxacc[4][2];
    #pragma unroll
    for (int i = 0; i < 4; ++i)
        #pragma unroll
        for (int m2 = 0; m2 < 2; ++m2) kxacc[i][m2] = (float4v){0.f, 0.f, 0.f, 0.f};
    const float4v zf = {0.f, 0.f, 0.f, 0.f};

    for (int ch = 0; ch < 8; ++ch) {
        const int nc = n0 + (ch << 5);
        __syncthreads();                       // xsT/Klt free from prev chunk
        // stage xsT[n][c] bf16 (pack c-pairs into u32 writes)
        #pragma unroll
        for (int i = 0; i < 16; ++i) {
            int p = t + (i << 8);
            int n_ = p & 31, cp = p >> 5;
            float v0 = xb[(size_t)(2 * cp) * NN + nc + n_];
            float v1 = xb[(size_t)(2 * cp + 1) * NN + nc + n_];
            *(unsigned int*)&xsT[n_ * 264 + 2 * cp] = pk2bf(v0, v1);
        }
        __syncthreads();

        // --- K phase: D_K[m 16mt..][n 16ct..] over K=256 ---
        float4v kacc = zf;
        const int ncol = 16 * ct + ln;
        #pragma unroll
        for (int ks = 0; ks < 8; ++ks) {
            short8 bfr = *(const short8*)&xsT[ncol * 264 + 32 * ks + 8 * q];
            kacc = __builtin_amdgcn_mfma_f32_16x16x32_bf16(wkf[ks], bfr, kacc, 0, 0, 0);
        }
        #pragma unroll
        for (int r = 0; r < 4; ++r) {
            float kv_ = softplusf(kacc[r] + bkr[r]);
            ksumacc[r] += kv_;
            Klt[(16 * mt + 4 * q + r) * 40 + ncol] = f2bf(kv_);
        }
        __syncthreads();

        // --- KX phase: D[e][m] += x[e][n]*K[m][n], K-dim = 32 (one mfma) ---
        #pragma unroll
        for (int i = 0; i < 4; ++i) {
            const int e = 16 * (4 * w + i) + ln;
            const float* xp = xb + (size_t)e * NN + nc + 8 * q;
            float4 xa = *(const float4*)xp;
            float4 xc = *(const float4*)(xp + 4);
            short8 af;
            af[0] = (short)f2bf(xa.x); af[1] = (short)f2bf(xa.y);
            af[2] = (short)f2bf(xa.z); af[3] = (short)f2bf(xa.w);
            af[4] = (short)f2bf(xc.x); af[5] = (short)f2bf(xc.y);
            af[6] = (short)f2bf(xc.z); af[7] = (short)f2bf(xc.w);
            #pragma unroll
            for (int m2 = 0; m2 < 2; ++m2) {
                short8 bfr = *(const short8*)&Klt[(16 * m2 + ln) * 40 + 8 * q];
                kxacc[i][m2] = __builtin_amdgcn_mfma_f32_16x16x32_bf16(af, bfr, kxacc[i][m2], 0, 0, 0);
            }
        }
    }

    // Ksum: reduce over the 16 lanes of each quad (cols n), atomic per m
    #pragma unroll
    for (int r = 0; r < 4; ++r) {
        float v = ksumacc[r];
        v += __shfl_xor(v, 1); v += __shfl_xor(v, 2);
        v += __shfl_xor(v, 4); v += __shfl_xor(v, 8);
        if (ln == 0) atomicAdd(&ksum[b * 32 + 16 * mt + 4 * q + r], v);
    }

    // KX epilogue: LDS transpose (KXs aliases xsT) then coalesced dump
    __syncthreads();
    #pragma unroll
    for (int i = 0; i < 4; ++i)
        #pragma unroll
        for (int m2 = 0; m2 < 2; ++m2)
            #pragma unroll
            for (int r = 0; r < 4; ++r)
                KXs[(16 * m2 + ln) * 260 + 16 * (4 * w + i) + 4 * q + r] = kxacc[i][m2][r];
    __syncthreads();
    if (use_part) {
        float* dst = part + (size_t)blockIdx.x * 8192;
        #pragma unroll
        for (int i = 0; i < 32; ++i) dst[i * 256 + t] = KXs[i * 260 + t];
    } else {
        float* dst = kxf + (size_t)b * 8192;
        #pragma unroll
        for (int i = 0; i < 32; ++i) atomicAdd(&dst[i * 256 + t], KXs[i * 260 + t]);
    }
}

// ---------------------------------------------------------------------------
// Kernel R: reduce 64 tile-partials per batch -> KX final. grid 256 x 256.
// ---------------------------------------------------------------------------
__global__ __launch_bounds__(256) void kR(const float* __restrict__ part,
                                          float* __restrict__ kxf)
{
    int idx = blockIdx.x * 256 + threadIdx.x;
    int b = idx >> 13, f = idx & 8191;
    float s = 0.f;
    #pragma unroll 8
    for (int tl = 0; tl < 64; ++tl)
        s += part[(size_t)(b * 64 + tl) * 8192 + f];
    kxf[idx] = s;
}

// ---------------------------------------------------------------------------
// Kernel B: KV[m][c] = sum_e KX[m][e]*wv[c][e] + bv[c]*Ksum[m].
// ---------------------------------------------------------------------------
__global__ __launch_bounds__(256) void kB(
    const float* __restrict__ kxf, const float* __restrict__ ksum,
    const float* __restrict__ wv, const float* __restrict__ bv,
    float* __restrict__ kv)
{
    __shared__ float wvT[256 * 33];
    __shared__ float kxs[32 * 257];

    const int t  = threadIdx.x;
    const int b  = blockIdx.x >> 3;
    const int c0 = (blockIdx.x & 7) << 5;

    #pragma unroll
    for (int i = 0; i < 32; ++i) {
        int f = t + (i << 8);
        int r = f >> 8, e = f & 255;
        wvT[e * 33 + r]  = wv[(size_t)(c0 + r) * 256 + e];
        kxs[r * 257 + e] = kxf[b * 8192 + f];
    }
    __syncthreads();

    const int cl = t & 31, mq = t >> 5;
    float a0 = 0.f, a1 = 0.f, a2 = 0.f, a3 = 0.f;
    for (int e = 0; e < 256; ++e) {
        float wvv = wvT[e * 33 + cl];
        a0 = fmaf(kxs[(mq     ) * 257 + e], wvv, a0);
        a1 = fmaf(kxs[(mq +  8) * 257 + e], wvv, a1);
        a2 = fmaf(kxs[(mq + 16) * 257 + e], wvv, a2);
        a3 = fmaf(kxs[(mq + 24) * 257 + e], wvv, a3);
    }
    const int c = c0 + cl;
    const float bvc = bv[c];
    const float* ks = ksum + b * 32;
    float* kvb = kv + (size_t)b * 8192;
    kvb[(mq     ) * 256 + c] = a0 + bvc * ks[mq     ];
    kvb[(mq +  8) * 256 + c] = a1 + bvc * ks[mq +  8];
    kvb[(mq + 16) * 256 + c] = a2 + bvc * ks[mq + 16];
    kvb[(mq + 24) * 256 + c] = a3 + bvc * ks[mq + 24];
}

// ---------------------------------------------------------------------------
// Kernel C (MFMA): per (b, 128-n tile), 4 chunks of 32 n.
//   Q = softplus(wq@x+bq); den[n] = Q.(Ksum+EPS);
//   out[c][n] = x[c][n] + (gamma/den[n]) * sum_m Q[m][n]*KV[m][c]
// P-phase mfma: D[c][n] = KV^T(c,m) x Q(m,n)  (K=32, one mfma per tile),
// oriented so stores are n-coalesced. block 256 = 4 waves, grid 1024.
// ---------------------------------------------------------------------------
__global__ __launch_bounds__(256) void kC(
    const float* __restrict__ x, const float* __restrict__ wq,
    const float* __restrict__ bq, const float* __restrict__ kv,
    const float* __restrict__ ksum, const float* __restrict__ gamma,
    float* __restrict__ out)
{
    __shared__ __align__(16) unsigned short xsT[32 * 264];  // [n][c] bf16
    __shared__ __align__(16) unsigned short Qs [32 * 40];   // [n][m] bf16
    __shared__ float denp[2 * 32];                          // [mt][n]

    const int t  = threadIdx.x;
    const int b  = blockIdx.x >> 7;
    const int n0 = (blockIdx.x & 127) << 5 << 2;            // tile*128
    const float* xb = x + (size_t)b * NC * NN;
    float* ob = out + (size_t)b * NC * NN;
    const float g = gamma[0];

    const int w = t >> 6, l = t & 63, q = l >> 4, ln = l & 15;
    const int mt = w & 1, ct = w >> 1;

    // preload wq A-frags (row m = 16mt+ln)
    short8 wqf[8];
    #pragma unroll
    for (int ks = 0; ks < 8; ++ks) {
        const float* wp = wq + (16 * mt + ln) * 256 + 32 * ks + 8 * q;
        float4 a = *(const float4*)wp;
        float4 c = *(const float4*)(wp + 4);
        short8 f;
        f[0] = (short)f2bf(a.x); f[1] = (short)f2bf(a.y);
        f[2] = (short)f2bf(a.z); f[3] = (short)f2bf(a.w);
        f[4] = (short)f2bf(c.x); f[5] = (short)f2bf(c.y);
        f[6] = (short)f2bf(c.z); f[7] = (short)f2bf(c.w);
        wqf[ks] = f;
    }
    float bqr[4], ksEr[4];
    #pragma unroll
    for (int r = 0; r < 4; ++r) {
        bqr[r]  = bq[16 * mt + 4 * q + r];
        ksEr[r] = ksum[b * 32 + 16 * mt + 4 * q + r] + EPSF;
    }
    // preload KV^T A-frags: per ct_c = 4w+cc: A[c=16ct_c+ln][k=m=8q+j]
    short8 kvf[4];
    #pragma unroll
    for (int cc = 0; cc < 4; ++cc) {
        const float* kp = kv + (size_t)b * 8192 + (8 * q) * 256 + 16 * (4 * w + cc) + ln;
        short8 f;
        #pragma unroll
        for (int j = 0; j < 8; ++j) f[j] = (short)f2bf(kp[j * 256]);
        kvf[cc] = f;
    }
    const float4v zf = {0.f, 0.f, 0.f, 0.f};

    for (int ch = 0; ch < 4; ++ch) {
        const int nc = n0 + (ch << 5);
        __syncthreads();                       // Qs/denp free, xsT free
        #pragma unroll
        for (int i = 0; i < 16; ++i) {
            int p = t + (i << 8);
            int n_ = p & 31, cp = p >> 5;
            float v0 = xb[(size_t)(2 * cp) * NN + nc + n_];
            float v1 = xb[(size_t)(2 * cp + 1) * NN + nc + n_];
            *(unsigned int*)&xsT[n_ * 264 + 2 * cp] = pk2bf(v0, v1);
        }
        __syncthreads();

        // --- Q phase ---
        float4v qacc = zf;
        const int ncol = 16 * ct + ln;
        #pragma unroll
        for (int ks = 0; ks < 8; ++ks) {
            short8 bfr = *(const short8*)&xsT[ncol * 264 + 32 * ks + 8 * q];
            qacc = __builtin_amdgcn_mfma_f32_16x16x32_bf16(wqf[ks], bfr, qacc, 0, 0, 0);
        }
        float dpart = 0.f;
        unsigned short qpk[4];
        #pragma unroll
        for (int r = 0; r < 4; ++r) {
            float qv = softplusf(qacc[r] + bqr[r]);
            dpart += qv * ksEr[r];
            qpk[r] = f2bf(qv);
        }
        *(unsigned int*)&Qs[ncol * 40 + 16 * mt + 4 * q]     = (unsigned int)qpk[0] | ((unsigned int)qpk[1] << 16);
        *(unsigned int*)&Qs[ncol * 40 + 16 * mt + 4 * q + 2] = (unsigned int)qpk[2] | ((unsigned int)qpk[3] << 16);
        dpart += __shfl_xor(dpart, 16);
        dpart += __shfl_xor(dpart, 32);
        if (l < 16) denp[mt * 32 + 16 * ct + l] = dpart;
        __syncthreads();

        // --- P phase: per (ct_n, ct_c): one K=32 mfma + epilogue ---
        #pragma unroll
        for (int ctn = 0; ctn < 2; ++ctn) {
            const int ncol2 = 16 * ctn + ln;
            const float den = denp[ncol2] + denp[32 + ncol2];
            const float nrm = g / den;
            short8 bqf = *(const short8*)&Qs[ncol2 * 40 + 8 * q];
            const int ngl = nc + ncol2;
            #pragma unroll
            for (int cc = 0; cc < 4; ++cc) {
                float4v p = __builtin_amdgcn_mfma_f32_16x16x32_bf16(kvf[cc], bqf, zf, 0, 0, 0);
                #pragma unroll
                for (int r = 0; r < 4; ++r) {
                    const int c = 16 * (4 * w + cc) + 4 * q + r;
                    size_t addr = (size_t)c * NN + ngl;
                    ob[addr] = xb[addr] + nrm * p[r];
                }
            }
        }
    }
}

// ---------------------------------------------------------------------------
extern "C" void kernel_launch(void* const* d_in, const int* in_sizes, int n_in,
                              void* d_out, int out_size, void* d_ws, size_t ws_size,
                              hipStream_t stream)
{
    (void)in_sizes; (void)n_in; (void)out_size;
    const float* x     = (const float*)d_in[0];
    const float* wq    = (const float*)d_in[1];
    const float* bq    = (const float*)d_in[2];
    const float* wk    = (const float*)d_in[3];
    const float* bk    = (const float*)d_in[4];
    const float* wv    = (const float*)d_in[5];
    const float* bv    = (const float*)d_in[6];
    const float* gamma = (const float*)d_in[7];
    float* out = (float*)d_out;

    char* ws = (char*)d_ws;
    float* kxf  = (float*)(ws);              // 8*8192 floats
    float* ksum = (float*)(ws + 262144);     // 256 floats
    float* kv   = (float*)(ws + 263168);     // 8*8192 floats
    float* part = (float*)(ws + 525312);     // 512*8192 floats (optional)
    const size_t need_part = 525312ull + 512ull * 8192ull * 4ull;
    const int use_part = (ws_size >= need_part) ? 1 : 0;

    hipMemsetAsync(ksum, 0, 1024, stream);
    if (!use_part) hipMemsetAsync(kxf, 0, 262144, stream);

    kA<<<dim3(512), dim3(256), 0, stream>>>(x, wk, bk, part, kxf, ksum, use_part);
    if (use_part) kR<<<dim3(256), dim3(256), 0, stream>>>(part, kxf);
    kB<<<dim3(64), dim3(256), 0, stream>>>(kxf, ksum, wv, bv, kv);
    kC<<<dim3(1024), dim3(256), 0, stream>>>(x, wq, bq, kv, ksum, gamma, out);
}